// Round 12
// baseline (251.434 us; speedup 1.0000x reference)
//
#include <hip/hip_runtime.h>
#include <hip/hip_fp16.h>
#include <math.h>

// FastRadonTransform via LDS-staged rotated-tile sampling, v10.
// Base = v6 (183 us): 48row x 64col window (stride 68, XOR+additive swizzle),
// adaptive lane mapping. NEW: f16 channel-pair packing. Two planes of 4B
// half2 slots: plane01=(c0,c1), plane2=(c2,0). Each bilinear corner = 2
// ds_read_b32 -> 8 LDS reads/sample (was 12), conflicts -33%, LDS 39.2->26.1KB
// -> 6 blocks/CU (was 4). f16 RTN error ~2^-11 * sqrt(384) ~ 0.04 << 1.63
// threshold. (v8's float2 failed because 8B elements use only even banks;
// half2 is 4B -> full 32-bank coverage, identical address algebra to v6.)

constexpr int B = 2, C = 3, H = 384, W = 384, K = 180;
constexpr int TILE = 32;
constexpr int NTW  = W / TILE;      // 12
constexpr int NTH  = H / TILE;      // 12
constexpr int ROWS = 48;
constexpr int STR  = 68;            // slot stride/row (68 mod 32 = 4: drift)
constexpr int PLN  = ROWS * STR;    // 3264 slots (4B each) per plane

struct Cat { int stage; int xal; int ym; };

__device__ __forceinline__ Cat tile_cat(float A, float Bc, float sth, float cth,
                                        int h0, int tw) {
    const float w0f = (float)(tw * TILE), w1f = w0f + (TILE - 1);
    const float h0f = (float)h0,          h1f = h0f + (TILE - 1);
    const float minfx = A  + fminf(w0f * cth, w1f * cth) + fminf(h0f * sth, h1f * sth);
    const float minfy = Bc + fminf(-w0f * sth, -w1f * sth) + fminf(h0f * cth, h1f * cth);
    Cat c;
    const int xm = (int)floorf(minfx) - 1;
    c.ym  = (int)floorf(minfy) - 1;
    c.xal = xm & ~3;
    const bool skip = (xm + 47 < 0) | (xm > W - 1) | (c.ym + 47 < 0) | (c.ym > H - 1);
    c.stage = skip ? 0 : 1;
    return c;
}

// Staging: u = tid + 256j (j<3), r = u>>4 in [0,48), g = u&15 in [0,16).
// Window: rows ym..ym+47, pixel cols xal..xal+63 (xal 4-aligned).
__device__ __forceinline__ void issue_loads(const float* __restrict__ img,
                                            int tid, int xal, int ym,
                                            float4 (&pf)[C][3]) {
    #pragma unroll
    for (int c = 0; c < C; ++c) {
        const float* __restrict__ plane = img + c * (H * W);
        #pragma unroll
        for (int j = 0; j < 3; ++j) {
            const int u = tid + 256 * j;
            const int r = u >> 4;
            const int g = u & 15;
            const int gy = min(max(ym + r, 0), H - 1);
            const int gx = min(max(xal + 4 * g, 0), W - 4);  // stays 4-aligned
            pf[c][j] = *reinterpret_cast<const float4*>(plane + gy * W + gx);
        }
    }
}

__device__ __forceinline__ uint32_t pkh2(float a, float b) {
    const __half2 h = __floats2half2_rn(a, b);
    return *reinterpret_cast<const uint32_t*>(&h);
}

__device__ __forceinline__ void write_stage(const float* __restrict__ img,
                                            uint32_t* __restrict__ sm01,
                                            uint32_t* __restrict__ sm2,
                                            int tid, int xal, int ym,
                                            const float4 (&pf)[C][3]) {
    const bool interior = (ym >= 0) & (ym <= H - ROWS) &
                          (xal >= 0) & (xal <= W - 64);
    #pragma unroll
    for (int j = 0; j < 3; ++j) {
        const int u = tid + 256 * j;
        const int r = u >> 4;
        const int g = u & 15;
        const int px = 4 * g;                  // 0..60, multiple of 4
        const int vc = (r & 7) << 2;           // 16B-granular swizzle
        const int bs = r * STR + (px ^ vc);    // slot index, multiple of 4
        const float4 q0 = pf[0][j];
        const float4 q1 = pf[1][j];
        const float4 q2 = pf[2][j];
        if (interior) {
            const uint4 u01 = make_uint4(pkh2(q0.x, q1.x), pkh2(q0.y, q1.y),
                                         pkh2(q0.z, q1.z), pkh2(q0.w, q1.w));
            const uint4 u2  = make_uint4(pkh2(q2.x, 0.f), pkh2(q2.y, 0.f),
                                         pkh2(q2.z, 0.f), pkh2(q2.w, 0.f));
            *reinterpret_cast<uint4*>(sm01 + bs) = u01;
            *reinterpret_cast<uint4*>(sm2  + bs) = u2;
        } else {
            const int gy = ym + r;
            const bool rowok = ((unsigned)gy < (unsigned)H);
            const int gyc = min(max(gy, 0), H - 1);
            const float* __restrict__ p0 = img + gyc * W;
            const float* __restrict__ p1 = p0 + H * W;
            const float* __restrict__ p2 = p1 + H * W;
            #pragma unroll
            for (int e = 0; e < 4; ++e) {
                const int gxe = xal + px + e;
                const bool ok = rowok && ((unsigned)gxe < (unsigned)W);
                const int gxc = min(max(gxe, 0), W - 1);
                const float t0 = ok ? p0[gxc] : 0.0f;
                const float t1 = ok ? p1[gxc] : 0.0f;
                const float t2 = ok ? p2[gxc] : 0.0f;
                sm01[bs + e] = pkh2(t0, t1);   // (px+e)^vc == (px^vc)+e
                sm2 [bs + e] = pkh2(t2, 0.f);
            }
        }
    }
}

__global__ __launch_bounds__(256) void radon_tile(
    const float* __restrict__ x,       // (B,C,H,W)
    const float* __restrict__ angles,  // (B,K)
    float* __restrict__ out)           // (B,C,H,K)
{
    __shared__ __align__(16) uint32_t smem[2 * PLN];   // 26112 B -> 6 blocks/CU
    uint32_t* sm01 = smem;
    uint32_t* sm2  = smem + PLN;

    const int bid = blockIdx.x;
    const int th  = bid % NTH;
    const int bk  = bid / NTH;
    const int k   = bk % K;
    const int b   = bk / K;

    const int tid = threadIdx.x;
    const int u1  = tid & 31;          // fine lane index (32 values)
    const int u8  = tid >> 5;          // group index (8 values)

    const float theta = angles[b * K + k] * (3.14159265358979323846f / 180.0f);
    float sth, cth;
    sincosf(theta, &sth, &cth);

    const float A  = 0.5f * (W - 1) * (1.0f - cth - sth);
    const float Bc = 0.5f * (H - 1) * (1.0f + sth - cth);

    // mapping select (block-uniform): lanes walk the axis with x-step >= .707
    const bool mapB = fabsf(sth) > fabsf(cth);
    const int wofs = mapB ? u8 : u1;
    const int hofs = mapB ? u1 : u8;
    const float dix = mapB ? 8.0f * cth :  8.0f * sth;
    const float diy = mapB ? -8.0f * sth : 8.0f * cth;

    const int h0 = th * TILE;
    const float hf = (float)(h0 + hofs);

    const float* __restrict__ img = x + (size_t)b * (C * H * W);

    float acc[4][C];
    #pragma unroll
    for (int i = 0; i < 4; ++i)
        #pragma unroll
        for (int c = 0; c < C; ++c) acc[i][c] = 0.0f;

    float4 pf[C][3];
    Cat cur = tile_cat(A, Bc, sth, cth, h0, 0);
    if (cur.stage) issue_loads(img, tid, cur.xal, cur.ym, pf);

    for (int tw = 0; tw < NTW; ++tw) {
        Cat nxt; nxt.stage = 0; nxt.xal = 0; nxt.ym = 0;
        if (tw + 1 < NTW) nxt = tile_cat(A, Bc, sth, cth, h0, tw + 1);

        if (cur.stage) {
            __syncthreads();                       // prior sampling done
            write_stage(img, sm01, sm2, tid, cur.xal, cur.ym, pf);
        }
        if (nxt.stage) issue_loads(img, tid, nxt.xal, nxt.ym, pf);  // overlap
        if (cur.stage) {
            __syncthreads();                       // LDS tile ready
            const float wf = (float)(tw * TILE + wofs);
            float fx = fmaf(hf, sth, fmaf(wf,  cth, A)) - (float)cur.xal;
            float fy = fmaf(hf, cth, fmaf(wf, -sth, Bc)) - (float)cur.ym;
            #pragma unroll
            for (int i = 0; i < 4; ++i) {
                const float xf = floorf(fx), yf = floorf(fy);
                const int lx = (int)xf;            // [1, 52] < 64
                const int ly = (int)yf;            // [1, 46] < 48
                const float wx1 = fx - xf, wy1 = fy - yf;
                const float wx0 = 1.0f - wx1, wy0 = 1.0f - wy1;
                const float w00 = wy0 * wx0, w01 = wy0 * wx1;
                const float w10 = wy1 * wx0, w11 = wy1 * wx1;
                const int row0 = ly * STR, row1 = row0 + STR;
                const int v0 = (ly & 7) << 2;
                const int v1 = ((ly + 1) & 7) << 2;
                const int s00 = row0 + ( lx      ^ v0);
                const int s01 = row0 + ((lx + 1) ^ v0);
                const int s10 = row1 + ( lx      ^ v1);
                const int s11 = row1 + ((lx + 1) ^ v1);
                const float2 p00 = __half22float2(*reinterpret_cast<const __half2*>(&sm01[s00]));
                const float2 p01 = __half22float2(*reinterpret_cast<const __half2*>(&sm01[s01]));
                const float2 p10 = __half22float2(*reinterpret_cast<const __half2*>(&sm01[s10]));
                const float2 p11 = __half22float2(*reinterpret_cast<const __half2*>(&sm01[s11]));
                const float2 q00 = __half22float2(*reinterpret_cast<const __half2*>(&sm2[s00]));
                const float2 q01 = __half22float2(*reinterpret_cast<const __half2*>(&sm2[s01]));
                const float2 q10 = __half22float2(*reinterpret_cast<const __half2*>(&sm2[s10]));
                const float2 q11 = __half22float2(*reinterpret_cast<const __half2*>(&sm2[s11]));
                acc[i][0] = fmaf(w00, p00.x, fmaf(w01, p01.x,
                            fmaf(w10, p10.x, fmaf(w11, p11.x, acc[i][0]))));
                acc[i][1] = fmaf(w00, p00.y, fmaf(w01, p01.y,
                            fmaf(w10, p10.y, fmaf(w11, p11.y, acc[i][1]))));
                acc[i][2] = fmaf(w00, q00.x, fmaf(w01, q01.x,
                            fmaf(w10, q10.x, fmaf(w11, q11.x, acc[i][2]))));
                fx += dix; fy += diy;
            }
        }
        cur = nxt;
    }

    if (!mapB) {
        // reduce over the 32 u1-lanes (w); xor masks <32 stay in each half
        #pragma unroll
        for (int i = 0; i < 4; ++i) {
            #pragma unroll
            for (int c = 0; c < C; ++c) {
                float s = acc[i][c];
                #pragma unroll
                for (int m = 16; m >= 1; m >>= 1) s += __shfl_xor(s, m, 64);
                if (u1 == 0) {
                    const int h = h0 + u8 + 8 * i;
                    out[((size_t)(b * C + c) * H + h) * K + k] = s;
                }
            }
        }
    } else {
        // each thread owns one h = h0+u1; sum its 4 w-chunks, then reduce
        // the 8 u8-groups through LDS (reused as f32 scratch; sync first).
        __syncthreads();
        float* red = reinterpret_cast<float*>(smem);
        #pragma unroll
        for (int c = 0; c < C; ++c) {
            const float s = (acc[0][c] + acc[1][c]) + (acc[2][c] + acc[3][c]);
            red[(c * 8 + u8) * 32 + u1] = s;
        }
        __syncthreads();
        if (tid < C * 32) {
            const int c = tid >> 5;
            const int l = tid & 31;
            float s = 0.0f;
            #pragma unroll
            for (int g = 0; g < 8; ++g) s += red[(c * 8 + g) * 32 + l];
            out[((size_t)(b * C + c) * H + (h0 + l)) * K + k] = s;
        }
    }
}

extern "C" void kernel_launch(void* const* d_in, const int* in_sizes, int n_in,
                              void* d_out, int out_size, void* d_ws, size_t ws_size,
                              hipStream_t stream) {
    const float* x      = (const float*)d_in[0];
    const float* angles = (const float*)d_in[1];
    float* out          = (float*)d_out;

    radon_tile<<<B * K * NTH, 256, 0, stream>>>(x, angles, out);  // 4320 blocks
}